// Round 1
// baseline (1688.094 us; speedup 1.0000x reference)
//
#include <hip/hip_runtime.h>
#include <cstddef>

#define NPIX 1024   // H*W = 32*32

// ---------------------------------------------------------------------------
// Workspace layout (float offsets). Pool = 37,748,736 floats = 151.0 MB.
//   [0        , 12582912)  qkv   (B x 768 x 1024)     -- phase A
//   [12582912 , 25165824)  dpw   (B x 768 x 1024)     -- phase A (dwconv5x5 out, grouped-pw in-place)
//   [25165824 , 33554432)  att   (B x 512 x 1024)     -- phase A
//   [33554432 , 37748736)  t1    (B x 256 x 1024)     -- live through both phases
//   [0        , 16777216)  h1    (B x 1024 x 1024)    -- phase B (aliases qkv + part of dpw)
//   [16777216 , 33554432)  h2    (B x 1024 x 1024)    -- phase B (aliases rest of dpw + att)
// ---------------------------------------------------------------------------
static constexpr size_t QKV_OFF = 0;
static constexpr size_t DPW_OFF = 12582912;
static constexpr size_t ATT_OFF = 25165824;
static constexpr size_t T1_OFF  = 33554432;
static constexpr size_t H1_OFF  = 0;
static constexpr size_t H2_OFF  = 16777216;

// ---------------------------------------------------------------------------
// GEMM: Y[b,o,n] = sum_c W[o,c] * X[b,c,n]   (+ fused epilogue)
// EPI: 0 = plain store
//      1 = batchnorm + residual (res[b,o,n]); ACC => Y += result else Y = result
//      2 = bias + hswish
// Tiles: BM=64 (o), BN=128 (n), BK=32. 256 threads, 8o x 4n per thread.
// ---------------------------------------------------------------------------
template<int EPI, bool ACC>
__global__ __launch_bounds__(256)
void gemm_f32(const float* __restrict__ X, const float* __restrict__ W,
              float* __restrict__ Y, const int O, const int K,
              const float* __restrict__ res,
              const float* __restrict__ bng, const float* __restrict__ bnb,
              const float* __restrict__ bnm, const float* __restrict__ bnv,
              const float* __restrict__ bias)
{
    __shared__ float Xs[32][128];
    __shared__ float Ws[32][68];   // [k][o], padded stride 68 (272B, 16B-aligned)

    const int t  = threadIdx.x;
    const int o0 = blockIdx.x * 64;
    const int j0 = blockIdx.y * 128;
    const int b  = j0 >> 10;
    const int n0 = j0 & 1023;

    const int cn = (t & 31) * 4;   // n within tile (4 per thread)
    const int co = (t >> 5) * 8;   // o within tile (8 per thread)

    float acc[8][4];
#pragma unroll
    for (int i = 0; i < 8; i++)
#pragma unroll
        for (int j = 0; j < 4; j++) acc[i][j] = 0.f;

    // staging maps
    const int xr = t >> 5;          // 0..7
    const int xc = (t & 31) * 4;    // 0..124
    const int wo = t >> 2;          // 0..63
    const int wk = (t & 3) * 8;     // 0,8,16,24

    const float* Xb = X + ((size_t)b * K) * NPIX + n0 + xc;
    const float* Wb = W + (size_t)(o0 + wo) * K + wk;

    for (int k0 = 0; k0 < K; k0 += 32) {
        __syncthreads();
#pragma unroll
        for (int r = 0; r < 4; r++) {
            const int row = xr + r * 8;
            const float4 v = *(const float4*)(Xb + (size_t)(k0 + row) * NPIX);
            *(float4*)(&Xs[row][xc]) = v;
        }
        {
            const float4 a = *(const float4*)(Wb + k0);
            const float4 c = *(const float4*)(Wb + k0 + 4);
            Ws[wk + 0][wo] = a.x; Ws[wk + 1][wo] = a.y;
            Ws[wk + 2][wo] = a.z; Ws[wk + 3][wo] = a.w;
            Ws[wk + 4][wo] = c.x; Ws[wk + 5][wo] = c.y;
            Ws[wk + 6][wo] = c.z; Ws[wk + 7][wo] = c.w;
        }
        __syncthreads();
#pragma unroll
        for (int kk = 0; kk < 32; kk++) {
            const float4 x4 = *(const float4*)(&Xs[kk][cn]);
            const float4 w0 = *(const float4*)(&Ws[kk][co]);
            const float4 w1 = *(const float4*)(&Ws[kk][co + 4]);
            const float xv[4] = {x4.x, x4.y, x4.z, x4.w};
            const float wv[8] = {w0.x, w0.y, w0.z, w0.w, w1.x, w1.y, w1.z, w1.w};
#pragma unroll
            for (int i = 0; i < 8; i++)
#pragma unroll
                for (int j = 0; j < 4; j++)
                    acc[i][j] = fmaf(wv[i], xv[j], acc[i][j]);
        }
    }

    const size_t ybase = ((size_t)b * O + o0 + co) * NPIX + n0 + cn;
#pragma unroll
    for (int i = 0; i < 8; i++) {
        const int o = o0 + co + i;
        float scale = 1.f, shift = 0.f;
        if (EPI == 1) {
            const float inv = bng[o] / sqrtf(bnv[o] + 1e-5f);
            scale = inv;
            shift = bnb[o] - bnm[o] * inv;
        } else if (EPI == 2) {
            shift = bias[o];
        }
        const size_t off = ybase + (size_t)i * NPIX;
        float out4[4];
#pragma unroll
        for (int j = 0; j < 4; j++) {
            float v = acc[i][j];
            if (EPI == 1) {
                v = v * scale + shift;
            } else if (EPI == 2) {
                v += shift;
                v = v * fminf(fmaxf(v + 3.f, 0.f), 6.f) * (1.f / 6.f);
            }
            out4[j] = v;
        }
        if (EPI == 1) {
            const float4 r0 = *(const float4*)(res + off);
            out4[0] += r0.x; out4[1] += r0.y; out4[2] += r0.z; out4[3] += r0.w;
        }
        if (ACC) {
            const float4 y0 = *(const float4*)(Y + off);
            out4[0] += y0.x; out4[1] += y0.y; out4[2] += y0.z; out4[3] += y0.w;
        }
        *(float4*)(Y + off) = make_float4(out4[0], out4[1], out4[2], out4[3]);
    }
}

// ---------------------------------------------------------------------------
// Depthwise 5x5 SAME (cross-correlation), one (b,c) 32x32 plane per block.
// ---------------------------------------------------------------------------
__global__ __launch_bounds__(256)
void dwconv5x5(const float* __restrict__ X, const float* __restrict__ Wd,
               float* __restrict__ Y)
{
    __shared__ float tile[36 * 36];
    __shared__ float wl[25];
    const int t  = threadIdx.x;
    const int bc = blockIdx.x;            // b*768 + c
    const int c  = bc % 768;
    const float* xp = X + (size_t)bc * NPIX;
    if (t < 25) wl[t] = Wd[c * 25 + t];
    for (int i = t; i < 36 * 36; i += 256) {
        const int r = i / 36 - 2;
        const int q = i % 36 - 2;
        tile[i] = (r >= 0 && r < 32 && q >= 0 && q < 32) ? xp[r * 32 + q] : 0.f;
    }
    __syncthreads();
#pragma unroll
    for (int p = 0; p < 4; p++) {
        const int px = t + p * 256;
        const int h = px >> 5, w = px & 31;
        float s = 0.f;
#pragma unroll
        for (int ky = 0; ky < 5; ky++)
#pragma unroll
            for (int kx = 0; kx < 5; kx++)
                s = fmaf(tile[(h + ky) * 36 + (w + kx)], wl[ky * 5 + kx], s);
        Y[(size_t)bc * NPIX + px] = s;
    }
}

// ---------------------------------------------------------------------------
// Depthwise 3x3 SAME + bias + hswish, one (b,c) plane per block.
// ---------------------------------------------------------------------------
__global__ __launch_bounds__(256)
void dwconv3x3_hsw(const float* __restrict__ X, const float* __restrict__ Wd,
                   const float* __restrict__ bias, float* __restrict__ Y)
{
    __shared__ float tile[34 * 34];
    __shared__ float wl[9];
    const int t  = threadIdx.x;
    const int bc = blockIdx.x;            // b*1024 + c
    const int c  = bc & 1023;
    const float* xp = X + (size_t)bc * NPIX;
    if (t < 9) wl[t] = Wd[c * 9 + t];
    const float bb = bias[c];
    for (int i = t; i < 34 * 34; i += 256) {
        const int r = i / 34 - 1;
        const int q = i % 34 - 1;
        tile[i] = (r >= 0 && r < 32 && q >= 0 && q < 32) ? xp[r * 32 + q] : 0.f;
    }
    __syncthreads();
#pragma unroll
    for (int p = 0; p < 4; p++) {
        const int px = t + p * 256;
        const int h = px >> 5, w = px & 31;
        float s = bb;
#pragma unroll
        for (int ky = 0; ky < 3; ky++)
#pragma unroll
            for (int kx = 0; kx < 3; kx++)
                s = fmaf(tile[(h + ky) * 34 + (w + kx)], wl[ky * 3 + kx], s);
        s = s * fminf(fmaxf(s + 3.f, 0.f), 6.f) * (1.f / 6.f);
        Y[(size_t)bc * NPIX + px] = s;
    }
}

// ---------------------------------------------------------------------------
// Grouped 32->32 1x1 (24 groups), in-place on D. One (b,g,256-pixel chunk)
// per block; each thread owns one pixel (exclusive -> in-place safe).
// ---------------------------------------------------------------------------
__global__ __launch_bounds__(256)
void grouped_pw(float* __restrict__ D, const float* __restrict__ Wg)
{
    __shared__ float ws[1024];
    const int t     = threadIdx.x;
    const int blk   = blockIdx.x;          // (b*24+g)*4 + chunk
    const int chunk = blk & 3;
    const int bg    = blk >> 2;
    const int g     = bg % 24;
    const int b     = bg / 24;
    for (int i = t; i < 1024; i += 256) ws[i] = Wg[g * 1024 + i];
    __syncthreads();
    const int px = chunk * 256 + t;
    float* dp = D + ((size_t)(b * 768 + g * 32)) * NPIX + px;
    float in[32];
#pragma unroll
    for (int i = 0; i < 32; i++) in[i] = dp[(size_t)i * NPIX];
#pragma unroll
    for (int o = 0; o < 32; o++) {
        float s = 0.f;
#pragma unroll
        for (int i = 0; i < 32; i++) s = fmaf(ws[o * 32 + i], in[i], s);
        dp[(size_t)o * NPIX] = s;
    }
}

// ---------------------------------------------------------------------------
// ReLU linear attention. One block per (b, head); head<8 reads qkv buffer,
// head>=8 reads the grouped-pw buffer (avoids materializing the concat).
// Phase 1: kv[33][32] = [V;1] @ relu(K)^T over N=1024 (chunked LDS staging).
// Phase 2: out[d,n] = sum_e kv[d,e]*relu(Q[e,n]); att = out[:32]/(out[32]+eps)
// ---------------------------------------------------------------------------
__global__ __launch_bounds__(256)
void relu_lin_attn(const float* __restrict__ qkv, const float* __restrict__ dpw,
                   float* __restrict__ att)
{
    __shared__ float Ks[32][130];   // stride 130: float2-aligned, 2-way banks (free)
    __shared__ float Vs[32][130];
    __shared__ float kvs[1056];     // [33][32] flat

    const int t = threadIdx.x;
    const int b = blockIdx.x >> 4;
    const int h = blockIdx.x & 15;

    const float* base = (h < 8)
        ? qkv + ((size_t)(b * 768 + h * 96)) * NPIX
        : dpw + ((size_t)(b * 768 + (h - 8) * 96)) * NPIX;
    const float* qp = base;
    const float* kp = base + 32 * NPIX;
    const float* vp = base + 64 * NPIX;

    float accP[4] = {0.f, 0.f, 0.f, 0.f};
    float accD = 0.f;

    const int srow = t >> 3;          // 0..31
    const int scol = (t & 7) * 16;    // 0..112

    for (int ch = 0; ch < 8; ch++) {
        const int nb = ch * 128;
        __syncthreads();
#pragma unroll
        for (int j = 0; j < 16; j += 2) {
            float2 kk = *(const float2*)(kp + (size_t)srow * NPIX + nb + scol + j);
            kk.x = fmaxf(kk.x, 0.f);
            kk.y = fmaxf(kk.y, 0.f);
            *(float2*)(&Ks[srow][scol + j]) = kk;
            const float2 vv = *(const float2*)(vp + (size_t)srow * NPIX + nb + scol + j);
            *(float2*)(&Vs[srow][scol + j]) = vv;
        }
        __syncthreads();
#pragma unroll
        for (int i = 0; i < 4; i++) {
            const int p = t + i * 256;
            const int d = p >> 5;
            const int e = p & 31;
            float a = 0.f;
            for (int nn = 0; nn < 128; nn += 2) {
                const float2 kk = *(const float2*)(&Ks[e][nn]);
                const float2 vv = *(const float2*)(&Vs[d][nn]);
                a = fmaf(vv.x, kk.x, a);
                a = fmaf(vv.y, kk.y, a);
            }
            accP[i] += a;
        }
        if (t < 32) {   // ones-row (d = 32): plain K column sums
            float a = 0.f;
            for (int nn = 0; nn < 128; nn += 2) {
                const float2 kk = *(const float2*)(&Ks[t][nn]);
                a += kk.x + kk.y;
            }
            accD += a;
        }
    }
    kvs[t]       = accP[0];
    kvs[t + 256] = accP[1];
    kvs[t + 512] = accP[2];
    kvs[t + 768] = accP[3];
    if (t < 32) kvs[1024 + t] = accD;
    __syncthreads();

    // phase 2: each thread owns 4 consecutive n
    const int n0 = t * 4;
    float4 qv[32];
#pragma unroll
    for (int e = 0; e < 32; e++) {
        float4 q = *(const float4*)(qp + (size_t)e * NPIX + n0);
        q.x = fmaxf(q.x, 0.f); q.y = fmaxf(q.y, 0.f);
        q.z = fmaxf(q.z, 0.f); q.w = fmaxf(q.w, 0.f);
        qv[e] = q;
    }
    float4 den = make_float4(0.f, 0.f, 0.f, 0.f);
#pragma unroll
    for (int e = 0; e < 32; e++) {
        const float w = kvs[1024 + e];
        den.x = fmaf(w, qv[e].x, den.x);
        den.y = fmaf(w, qv[e].y, den.y);
        den.z = fmaf(w, qv[e].z, den.z);
        den.w = fmaf(w, qv[e].w, den.w);
    }
    const float4 inv = make_float4(1.f / (den.x + 1e-15f), 1.f / (den.y + 1e-15f),
                                   1.f / (den.z + 1e-15f), 1.f / (den.w + 1e-15f));
    float* op = att + ((size_t)(b * 512 + h * 32)) * NPIX + n0;
    for (int d = 0; d < 32; d++) {
        float4 a = make_float4(0.f, 0.f, 0.f, 0.f);
#pragma unroll
        for (int e = 0; e < 32; e++) {
            const float w = kvs[d * 32 + e];
            a.x = fmaf(w, qv[e].x, a.x);
            a.y = fmaf(w, qv[e].y, a.y);
            a.z = fmaf(w, qv[e].z, a.z);
            a.w = fmaf(w, qv[e].w, a.w);
        }
        a.x *= inv.x; a.y *= inv.y; a.z *= inv.z; a.w *= inv.w;
        *(float4*)(op + (size_t)d * NPIX) = a;
    }
}

// ---------------------------------------------------------------------------
extern "C" void kernel_launch(void* const* d_in, const int* in_sizes, int n_in,
                              void* d_out, int out_size, void* d_ws, size_t ws_size,
                              hipStream_t stream)
{
    (void)in_sizes; (void)n_in; (void)out_size; (void)ws_size;

    const float* x      = (const float*)d_in[0];
    const float* y      = (const float*)d_in[1];
    const float* qkv_w  = (const float*)d_in[2];
    const float* dw5_w  = (const float*)d_in[3];
    const float* pwg_w  = (const float*)d_in[4];
    const float* proj_w = (const float*)d_in[5];
    const float* proj_g = (const float*)d_in[6];
    const float* proj_b = (const float*)d_in[7];
    const float* proj_m = (const float*)d_in[8];
    const float* proj_v = (const float*)d_in[9];
    const float* inv_w  = (const float*)d_in[10];
    const float* inv_b  = (const float*)d_in[11];
    const float* dwc_w  = (const float*)d_in[12];
    const float* dwc_b  = (const float*)d_in[13];
    const float* pw_w   = (const float*)d_in[14];
    const float* pw_g   = (const float*)d_in[15];
    const float* pw_b   = (const float*)d_in[16];
    const float* pw_m   = (const float*)d_in[17];
    const float* pw_v   = (const float*)d_in[18];

    float* ws   = (float*)d_ws;
    float* wqkv = ws + QKV_OFF;
    float* wdpw = ws + DPW_OFF;
    float* watt = ws + ATT_OFF;
    float* wt1  = ws + T1_OFF;
    float* wh1  = ws + H1_OFF;
    float* wh2  = ws + H2_OFF;
    float* out  = (float*)d_out;

    for (int blk = 0; blk < 2; blk++) {
        const float* t = (blk == 0) ? x : y;

        // --- lite_mla ---
        gemm_f32<0, false><<<dim3(12, 128), 256, 0, stream>>>(
            t, qkv_w, wqkv, 768, 256,
            nullptr, nullptr, nullptr, nullptr, nullptr, nullptr);
        dwconv5x5<<<dim3(12288), 256, 0, stream>>>(wqkv, dw5_w, wdpw);
        grouped_pw<<<dim3(1536), 256, 0, stream>>>(wdpw, pwg_w);
        relu_lin_attn<<<dim3(256), 256, 0, stream>>>(wqkv, wdpw, watt);
        gemm_f32<1, false><<<dim3(4, 128), 256, 0, stream>>>(
            watt, proj_w, wt1, 256, 512,
            t, proj_g, proj_b, proj_m, proj_v, nullptr);

        // --- mbconv ---
        gemm_f32<2, false><<<dim3(16, 128), 256, 0, stream>>>(
            wt1, inv_w, wh1, 1024, 256,
            nullptr, nullptr, nullptr, nullptr, nullptr, inv_b);
        dwconv3x3_hsw<<<dim3(16384), 256, 0, stream>>>(wh1, dwc_w, dwc_b, wh2);
        if (blk == 0) {
            gemm_f32<1, false><<<dim3(4, 128), 256, 0, stream>>>(
                wh2, pw_w, out, 256, 1024,
                wt1, pw_g, pw_b, pw_m, pw_v, nullptr);
        } else {
            gemm_f32<1, true><<<dim3(4, 128), 256, 0, stream>>>(
                wh2, pw_w, out, 256, 1024,
                wt1, pw_g, pw_b, pw_m, pw_v, nullptr);
        }
    }
}

// Round 2
// 593.481 us; speedup vs baseline: 2.8444x; 2.8444x over previous
//
#include <hip/hip_runtime.h>
#include <cstddef>

#define NPIX 1024   // H*W = 32*32

// ---------------------------------------------------------------------------
// Workspace layout (float offsets). Pool = 37,748,736 floats = 151.0 MB.
//   [0        , 12582912)  qkv   (B x 768 x 1024)     -- phase A
//   [12582912 , 25165824)  dpw   (B x 768 x 1024)     -- phase A
//   [25165824 , 33554432)  att   (B x 512 x 1024)     -- phase A
//   [33554432 , 37748736)  t1    (B x 256 x 1024)     -- live through both phases
//        kvp (2048 x 1056 = 2.16M floats) aliases t1: dead before proj writes t1
//   [0        , 16777216)  h1    (B x 1024 x 1024)    -- phase B
//   [16777216 , 33554432)  h2    (B x 1024 x 1024)    -- phase B
// ---------------------------------------------------------------------------
static constexpr size_t QKV_OFF = 0;
static constexpr size_t DPW_OFF = 12582912;
static constexpr size_t ATT_OFF = 25165824;
static constexpr size_t T1_OFF  = 33554432;
static constexpr size_t H1_OFF  = 0;
static constexpr size_t H2_OFF  = 16777216;

typedef __attribute__((ext_vector_type(8))) short bf16x8;
typedef __attribute__((ext_vector_type(4))) float f32x4;

__device__ inline unsigned short f2bf(float f) {
    union { float f; unsigned int u; } v; v.f = f;
    unsigned int u = v.u;
    u += 0x7FFFu + ((u >> 16) & 1u);        // round-to-nearest-even
    return (unsigned short)(u >> 16);
}
__device__ inline unsigned int pk2(float a, float b) {
    return (unsigned int)f2bf(a) | ((unsigned int)f2bf(b) << 16);
}

// ---------------------------------------------------------------------------
// MFMA GEMM: Y[b,o,n] = sum_c W[o,c] * X[b,c,n]  (+ fused epilogue), bf16 MACs,
// fp32 buffers (convert during LDS staging).
// Block tile 128o x 128n, 4 waves (2x2), wave tile 64x64 = 4x4 frags 16x16x32.
// LDS: As[o][k] (W already k-contiguous), Bs[n][k] (X transposed while packing
// bf16 pairs along k -> ds_write_b128, no scattered 16-bit writes).
// Stride 40 ushort = 80B: every frag b128 read/write 16B-aligned, ~bank-floor.
// EPI: 0 = plain, 1 = BN + residual (+ACC), 2 = bias + hswish.
// ---------------------------------------------------------------------------
template<int EPI, bool ACC>
__global__ __launch_bounds__(256)
void gemm_bf16(const float* __restrict__ X, const float* __restrict__ W,
               float* __restrict__ Y, const int O, const int K,
               const float* __restrict__ res,
               const float* __restrict__ bng, const float* __restrict__ bnb,
               const float* __restrict__ bnm, const float* __restrict__ bnv,
               const float* __restrict__ bias)
{
    __shared__ unsigned short As[128][40];
    __shared__ unsigned short Bs[128][40];

    const int t    = threadIdx.x;
    const int lane = t & 63;
    const int w    = t >> 6;
    const int o0   = blockIdx.x * 128;
    const int j0   = blockIdx.y * 128;
    const int b    = j0 >> 10;
    const int n0   = j0 & 1023;

    const int wo = (w >> 1) * 64;
    const int wn = (w & 1) * 64;

    f32x4 acc[4][4];
#pragma unroll
    for (int i = 0; i < 4; i++)
#pragma unroll
        for (int j = 0; j < 4; j++) {
            f32x4 z = {0.f, 0.f, 0.f, 0.f};
            acc[i][j] = z;
        }

    // staging maps
    const int ao = t >> 3;          // 0..31 (+32 per pass)
    const int ak = (t & 7) * 4;     // 0..28
    const int bn = (t & 63) * 2;    // 0..126
    const int bk = (t >> 6) * 8;    // 0,8,16,24

    const float* Xb = X + (size_t)b * K * NPIX + n0 + bn;

    const int l16  = lane & 15;
    const int koct = (lane >> 4) * 8;

    for (int k0 = 0; k0 < K; k0 += 32) {
        __syncthreads();
        // ---- stage A: W[o0+o][k0+ak .. +3] -> As[o][ak..] (coalesced 128B rows)
#pragma unroll
        for (int p = 0; p < 4; p++) {
            const int o = ao + p * 32;
            const float4 wv = *(const float4*)(W + (size_t)(o0 + o) * K + k0 + ak);
            uint2 d;
            d.x = pk2(wv.x, wv.y);
            d.y = pk2(wv.z, wv.w);
            *(uint2*)(&As[o][ak]) = d;
        }
        // ---- stage B (transpose): X[k0+bk+j][n0+bn,+1] -> Bs[bn][bk..], Bs[bn+1][bk..]
        {
            float2 f[8];
#pragma unroll
            for (int j = 0; j < 8; j++)
                f[j] = *(const float2*)(Xb + (size_t)(k0 + bk + j) * NPIX);
            uint4 c0, c1;
            c0.x = pk2(f[0].x, f[1].x); c0.y = pk2(f[2].x, f[3].x);
            c0.z = pk2(f[4].x, f[5].x); c0.w = pk2(f[6].x, f[7].x);
            c1.x = pk2(f[0].y, f[1].y); c1.y = pk2(f[2].y, f[3].y);
            c1.z = pk2(f[4].y, f[5].y); c1.w = pk2(f[6].y, f[7].y);
            *(uint4*)(&Bs[bn][bk])     = c0;
            *(uint4*)(&Bs[bn + 1][bk]) = c1;
        }
        __syncthreads();

        // ---- fragments + MFMA
        bf16x8 afr[4], bfr[4];
#pragma unroll
        for (int i = 0; i < 4; i++)
            afr[i] = *(const bf16x8*)(&As[wo + i * 16 + l16][koct]);
#pragma unroll
        for (int j = 0; j < 4; j++)
            bfr[j] = *(const bf16x8*)(&Bs[wn + j * 16 + l16][koct]);
#pragma unroll
        for (int i = 0; i < 4; i++)
#pragma unroll
            for (int j = 0; j < 4; j++)
                acc[i][j] = __builtin_amdgcn_mfma_f32_16x16x32_bf16(
                    afr[i], bfr[j], acc[i][j], 0, 0, 0);
    }

    // ---- epilogue. C/D layout: col = lane&15, row = (lane>>4)*4 + reg.
    const int r0 = (lane >> 4) * 4;
    float scale[4][4], shift[4][4];
    if (EPI == 1) {
#pragma unroll
        for (int i = 0; i < 4; i++)
#pragma unroll
            for (int r = 0; r < 4; r++) {
                const int o = o0 + wo + i * 16 + r0 + r;
                const float inv = bng[o] / sqrtf(bnv[o] + 1e-5f);
                scale[i][r] = inv;
                shift[i][r] = bnb[o] - bnm[o] * inv;
            }
    } else if (EPI == 2) {
#pragma unroll
        for (int i = 0; i < 4; i++)
#pragma unroll
            for (int r = 0; r < 4; r++)
                shift[i][r] = bias[o0 + wo + i * 16 + r0 + r];
    }
#pragma unroll
    for (int i = 0; i < 4; i++) {
#pragma unroll
        for (int j = 0; j < 4; j++) {
            const int nn = n0 + wn + j * 16 + l16;
            const size_t base = ((size_t)b * O + o0 + wo + i * 16 + r0) * NPIX + nn;
#pragma unroll
            for (int r = 0; r < 4; r++) {
                const size_t off = base + (size_t)r * NPIX;
                float v = acc[i][j][r];
                if (EPI == 1) {
                    v = v * scale[i][r] + shift[i][r] + res[off];
                } else if (EPI == 2) {
                    v += shift[i][r];
                    v = v * fminf(fmaxf(v + 3.f, 0.f), 6.f) * (1.f / 6.f);
                }
                if (ACC) v += Y[off];
                Y[off] = v;
            }
        }
    }
}

// ---------------------------------------------------------------------------
// Depthwise 5x5 SAME, one (b,c) 32x32 plane per block.
// ---------------------------------------------------------------------------
__global__ __launch_bounds__(256)
void dwconv5x5(const float* __restrict__ X, const float* __restrict__ Wd,
               float* __restrict__ Y)
{
    __shared__ float tile[36 * 36];
    __shared__ float wl[25];
    const int t  = threadIdx.x;
    const int bc = blockIdx.x;            // b*768 + c
    const int c  = bc % 768;
    const float* xp = X + (size_t)bc * NPIX;
    if (t < 25) wl[t] = Wd[c * 25 + t];
    for (int i = t; i < 36 * 36; i += 256) {
        const int r = i / 36 - 2;
        const int q = i % 36 - 2;
        tile[i] = (r >= 0 && r < 32 && q >= 0 && q < 32) ? xp[r * 32 + q] : 0.f;
    }
    __syncthreads();
#pragma unroll
    for (int p = 0; p < 4; p++) {
        const int px = t + p * 256;
        const int h = px >> 5, w = px & 31;
        float s = 0.f;
#pragma unroll
        for (int ky = 0; ky < 5; ky++)
#pragma unroll
            for (int kx = 0; kx < 5; kx++)
                s = fmaf(tile[(h + ky) * 36 + (w + kx)], wl[ky * 5 + kx], s);
        Y[(size_t)bc * NPIX + px] = s;
    }
}

// ---------------------------------------------------------------------------
// Depthwise 3x3 SAME + bias + hswish, one (b,c) plane per block.
// ---------------------------------------------------------------------------
__global__ __launch_bounds__(256)
void dwconv3x3_hsw(const float* __restrict__ X, const float* __restrict__ Wd,
                   const float* __restrict__ bias, float* __restrict__ Y)
{
    __shared__ float tile[34 * 34];
    __shared__ float wl[9];
    const int t  = threadIdx.x;
    const int bc = blockIdx.x;            // b*1024 + c
    const int c  = bc & 1023;
    const float* xp = X + (size_t)bc * NPIX;
    if (t < 9) wl[t] = Wd[c * 9 + t];
    const float bb = bias[c];
    for (int i = t; i < 34 * 34; i += 256) {
        const int r = i / 34 - 1;
        const int q = i % 34 - 1;
        tile[i] = (r >= 0 && r < 32 && q >= 0 && q < 32) ? xp[r * 32 + q] : 0.f;
    }
    __syncthreads();
#pragma unroll
    for (int p = 0; p < 4; p++) {
        const int px = t + p * 256;
        const int h = px >> 5, w = px & 31;
        float s = bb;
#pragma unroll
        for (int ky = 0; ky < 3; ky++)
#pragma unroll
            for (int kx = 0; kx < 3; kx++)
                s = fmaf(tile[(h + ky) * 34 + (w + kx)], wl[ky * 3 + kx], s);
        s = s * fminf(fmaxf(s + 3.f, 0.f), 6.f) * (1.f / 6.f);
        Y[(size_t)bc * NPIX + px] = s;
    }
}

// ---------------------------------------------------------------------------
// Grouped 32->32 1x1 (24 groups), in-place on D.
// ---------------------------------------------------------------------------
__global__ __launch_bounds__(256)
void grouped_pw(float* __restrict__ D, const float* __restrict__ Wg)
{
    __shared__ float ws[1024];
    const int t     = threadIdx.x;
    const int blk   = blockIdx.x;          // (b*24+g)*4 + chunk
    const int chunk = blk & 3;
    const int bg    = blk >> 2;
    const int g     = bg % 24;
    const int b     = bg / 24;
    for (int i = t; i < 1024; i += 256) ws[i] = Wg[g * 1024 + i];
    __syncthreads();
    const int px = chunk * 256 + t;
    float* dp = D + ((size_t)(b * 768 + g * 32)) * NPIX + px;
    float in[32];
#pragma unroll
    for (int i = 0; i < 32; i++) in[i] = dp[(size_t)i * NPIX];
#pragma unroll
    for (int o = 0; o < 32; o++) {
        float s = 0.f;
#pragma unroll
        for (int i = 0; i < 32; i++) s = fmaf(ws[o * 32 + i], in[i], s);
        dp[(size_t)o * NPIX] = s;
    }
}

// ---------------------------------------------------------------------------
// Attention phase 1: partial kv[33][32] per (b,h,chunk-of-128-pixels).
// kv[d][e] = sum_n V[d][n]*relu(K[e][n]);  row 32 (ones) = sum_n relu(K[e][n]).
// Deterministic: partials to kvp, reduced in phase 2 (no float atomics).
// ---------------------------------------------------------------------------
__global__ __launch_bounds__(256)
void attn_kv_partial(const float* __restrict__ qkv, const float* __restrict__ dpw,
                     float* __restrict__ kvp)
{
    __shared__ float Ks[32][130];
    __shared__ float Vs[32][130];
    const int t   = threadIdx.x;
    const int blk = blockIdx.x;           // bh*8 + ch
    const int ch  = blk & 7;
    const int bh  = blk >> 3;
    const int b   = bh >> 4;
    const int h   = bh & 15;
    const float* base = (h < 8)
        ? qkv + ((size_t)(b * 768 + h * 96)) * NPIX
        : dpw + ((size_t)(b * 768 + (h - 8) * 96)) * NPIX;
    const float* kp = base + 32 * NPIX + ch * 128;
    const float* vp = base + 64 * NPIX + ch * 128;
    const int srow = t >> 3;              // 0..31
    const int scol = (t & 7) * 16;        // 0..112
#pragma unroll
    for (int j = 0; j < 16; j += 2) {
        float2 kk = *(const float2*)(kp + (size_t)srow * NPIX + scol + j);
        kk.x = fmaxf(kk.x, 0.f);
        kk.y = fmaxf(kk.y, 0.f);
        *(float2*)(&Ks[srow][scol + j]) = kk;
        *(float2*)(&Vs[srow][scol + j]) =
            *(const float2*)(vp + (size_t)srow * NPIX + scol + j);
    }
    __syncthreads();
    float* outp = kvp + (size_t)blk * 1056;
#pragma unroll
    for (int i = 0; i < 4; i++) {
        const int p = t + i * 256;
        const int d = p >> 5;
        const int e = p & 31;
        float a = 0.f;
        for (int nn = 0; nn < 128; nn += 2) {
            const float2 kk = *(const float2*)(&Ks[e][nn]);
            const float2 vv = *(const float2*)(&Vs[d][nn]);
            a = fmaf(vv.x, kk.x, a);
            a = fmaf(vv.y, kk.y, a);
        }
        outp[p] = a;
    }
    if (t < 32) {
        float a = 0.f;
        for (int nn = 0; nn < 128; nn += 2) {
            const float2 kk = *(const float2*)(&Ks[t][nn]);
            a += kk.x + kk.y;
        }
        outp[1024 + t] = a;
    }
}

// ---------------------------------------------------------------------------
// Attention phase 2: reduce kv partials (LDS), then per-pixel
// out[d,n] = (sum_e kv[d,e]*relu(Q[e,n])) / (sum_e kv[32,e]*relu(Q[e,n]) + eps)
// 1 pixel/thread -> q[32] = 32 VGPRs, no spills; kv via LDS broadcast.
// ---------------------------------------------------------------------------
__global__ __launch_bounds__(256)
void attn_apply(const float* __restrict__ qkv, const float* __restrict__ dpw,
                const float* __restrict__ kvp, float* __restrict__ att)
{
    __shared__ float kvs[1056];
    const int t   = threadIdx.x;
    const int blk = blockIdx.x;           // bh*4 + qc
    const int qc  = blk & 3;
    const int bh  = blk >> 2;
    const int b   = bh >> 4;
    const int h   = bh & 15;
    for (int idx = t; idx < 1056; idx += 256) {
        float s = 0.f;
#pragma unroll
        for (int ch = 0; ch < 8; ch++)
            s += kvp[((size_t)bh * 8 + ch) * 1056 + idx];
        kvs[idx] = s;
    }
    __syncthreads();
    const float* qp = (h < 8)
        ? qkv + ((size_t)(b * 768 + h * 96)) * NPIX
        : dpw + ((size_t)(b * 768 + (h - 8) * 96)) * NPIX;
    const int n = qc * 256 + t;
    float q[32];
#pragma unroll
    for (int e = 0; e < 32; e++) q[e] = fmaxf(qp[(size_t)e * NPIX + n], 0.f);
    float den = 0.f;
#pragma unroll
    for (int e = 0; e < 32; e++) den = fmaf(kvs[1024 + e], q[e], den);
    const float inv = 1.f / (den + 1e-15f);
    float* op = att + ((size_t)(b * 512 + h * 32)) * NPIX + n;
    for (int d = 0; d < 32; d++) {
        float a = 0.f;
#pragma unroll
        for (int e = 0; e < 32; e++) a = fmaf(kvs[d * 32 + e], q[e], a);
        op[(size_t)d * NPIX] = a * inv;
    }
}

// ---------------------------------------------------------------------------
extern "C" void kernel_launch(void* const* d_in, const int* in_sizes, int n_in,
                              void* d_out, int out_size, void* d_ws, size_t ws_size,
                              hipStream_t stream)
{
    (void)in_sizes; (void)n_in; (void)out_size; (void)ws_size;

    const float* x      = (const float*)d_in[0];
    const float* y      = (const float*)d_in[1];
    const float* qkv_w  = (const float*)d_in[2];
    const float* dw5_w  = (const float*)d_in[3];
    const float* pwg_w  = (const float*)d_in[4];
    const float* proj_w = (const float*)d_in[5];
    const float* proj_g = (const float*)d_in[6];
    const float* proj_b = (const float*)d_in[7];
    const float* proj_m = (const float*)d_in[8];
    const float* proj_v = (const float*)d_in[9];
    const float* inv_w  = (const float*)d_in[10];
    const float* inv_b  = (const float*)d_in[11];
    const float* dwc_w  = (const float*)d_in[12];
    const float* dwc_b  = (const float*)d_in[13];
    const float* pw_w   = (const float*)d_in[14];
    const float* pw_g   = (const float*)d_in[15];
    const float* pw_b   = (const float*)d_in[16];
    const float* pw_m   = (const float*)d_in[17];
    const float* pw_v   = (const float*)d_in[18];

    float* ws   = (float*)d_ws;
    float* wqkv = ws + QKV_OFF;
    float* wdpw = ws + DPW_OFF;
    float* watt = ws + ATT_OFF;
    float* wt1  = ws + T1_OFF;
    float* wkvp = ws + T1_OFF;    // aliases t1 (dead until proj writes it)
    float* wh1  = ws + H1_OFF;
    float* wh2  = ws + H2_OFF;
    float* out  = (float*)d_out;

    for (int blk = 0; blk < 2; blk++) {
        const float* t = (blk == 0) ? x : y;

        // --- lite_mla ---
        gemm_bf16<0, false><<<dim3(6, 128), 256, 0, stream>>>(
            t, qkv_w, wqkv, 768, 256,
            nullptr, nullptr, nullptr, nullptr, nullptr, nullptr);
        dwconv5x5<<<dim3(12288), 256, 0, stream>>>(wqkv, dw5_w, wdpw);
        grouped_pw<<<dim3(1536), 256, 0, stream>>>(wdpw, pwg_w);
        attn_kv_partial<<<dim3(2048), 256, 0, stream>>>(wqkv, wdpw, wkvp);
        attn_apply<<<dim3(1024), 256, 0, stream>>>(wqkv, wdpw, wkvp, watt);
        gemm_bf16<1, false><<<dim3(2, 128), 256, 0, stream>>>(
            watt, proj_w, wt1, 256, 512,
            t, proj_g, proj_b, proj_m, proj_v, nullptr);

        // --- mbconv ---
        gemm_bf16<2, false><<<dim3(8, 128), 256, 0, stream>>>(
            wt1, inv_w, wh1, 1024, 256,
            nullptr, nullptr, nullptr, nullptr, nullptr, inv_b);
        dwconv3x3_hsw<<<dim3(16384), 256, 0, stream>>>(wh1, dwc_w, dwc_b, wh2);
        if (blk == 0) {
            gemm_bf16<1, false><<<dim3(2, 128), 256, 0, stream>>>(
                wh2, pw_w, out, 256, 1024,
                wt1, pw_g, pw_b, pw_m, pw_v, nullptr);
        } else {
            gemm_bf16<1, true><<<dim3(2, 128), 256, 0, stream>>>(
                wh2, pw_w, out, 256, 1024,
                wt1, pw_g, pw_b, pw_m, pw_v, nullptr);
        }
    }
}